// Round 8
// baseline (474.554 us; speedup 1.0000x reference)
//
#include <hip/hip_runtime.h>
#include <hip/hip_bf16.h>
#include <math.h>

// Problem constants (fixed by the reference).
constexpr int N  = 100000;   // nodes
constexpr int E  = 1600000;  // edges
constexpr int NG = 512;      // graphs
constexpr int NF = 64;
constexpr int H1 = 128;
constexpr int H2 = 64;

// CSR bucket binning
constexpr int BW   = 128;                 // nodes per bucket (dst >> 7)
constexpr int NB   = (N + BW - 1) / BW;   // 782 buckets
constexpr int CAP  = 2600;                // per-bucket edge capacity (mean 2046 + 12 sigma)
constexpr int CHUNK = 2048;               // edges per bin_scatter block (782 blocks ~ 3/CU)

// Set2Set LDS node cache
constexpr int MAXN = 416;                 // mean 195 + 15.8 sigma; global fallback beyond
constexpr int RST  = 68;                  // row stride in ushorts

typedef __attribute__((ext_vector_type(8))) short short8;
typedef __attribute__((ext_vector_type(4))) float f32x4;

__device__ __forceinline__ float gelu_f(float x) {
    return 0.5f * x * (1.0f + erff(x * 0.70710678118654752f));
}
__device__ __forceinline__ float sigmoid_f(float x) {
    return 1.0f / (1.0f + expf(-x));
}
__device__ __forceinline__ float waveAllSum(float v) {
    #pragma unroll
    for (int m = 32; m; m >>= 1) v += __shfl_xor(v, m);
    return v;
}
__device__ __forceinline__ unsigned short f2bf(float x) {
    __hip_bfloat16 b = __float2bfloat16(x);
    return *reinterpret_cast<unsigned short*>(&b);
}
__device__ __forceinline__ float bf2f(unsigned short u) {
    return __uint_as_float(((unsigned int)u) << 16);
}
__device__ __forceinline__ float bf_lo(unsigned int u) { return __uint_as_float(u << 16); }
__device__ __forceinline__ float bf_hi(unsigned int u) { return __uint_as_float(u & 0xffff0000u); }

// split v into bf16 hi + bf16 lo (v ~= hi + lo)
__device__ __forceinline__ void bfsplit(float v, unsigned short& hi, unsigned short& lo) {
    hi = f2bf(v);
    lo = f2bf(v - bf2f(hi));
}

// ---------------- fused setup: bucket cursors + graph ranges + LSTM weight transpose ----
__global__ __launch_bounds__(256) void setup_kernel(const int* __restrict__ batch,
                                                    const float* __restrict__ Wih0, const float* __restrict__ Whh0,
                                                    const float* __restrict__ bih0, const float* __restrict__ bhh0,
                                                    const float* __restrict__ Wih1, const float* __restrict__ Whh1,
                                                    const float* __restrict__ bih1, const float* __restrict__ bhh1,
                                                    float* __restrict__ WT0, float* __restrict__ WT1,
                                                    float* __restrict__ b0, float* __restrict__ b1,
                                                    int* __restrict__ bcursor, int* __restrict__ gstart) {
    int i = blockIdx.x * 256 + threadIdx.x;
    if (i < 192 * 256) {
        int k = i >> 8, j = i & 255;
        WT0[i] = (k < 128) ? Wih0[j * 128 + k] : Whh0[j * 64 + (k - 128)];
    }
    if (i < 128 * 256) {
        int k = i >> 8, j = i & 255;
        WT1[i] = (k < 64) ? Wih1[j * 64 + k] : Whh1[j * 64 + (k - 64)];
    }
    if (i < 256) { b0[i] = bih0[i] + bhh0[i]; b1[i] = bih1[i] + bhh1[i]; }
    if (i < NB) bcursor[i] = i * CAP;
    if (i <= NG) {
        if (i == NG) gstart[NG] = N;
        else {
            int lo = 0, hi = N;
            while (lo < hi) {
                int mid = (lo + hi) >> 1;
                if (batch[mid] < i) lo = mid + 1; else hi = mid;
            }
            gstart[i] = lo;
        }
    }
}

// ---------------- CSR build, phase 1: bin edges into bucket-strided packed (src<<7|dstlow) ----
__global__ __launch_bounds__(256) void bin_scatter_kernel(const int* __restrict__ ei,
                                                          int* __restrict__ bcursor,
                                                          int* __restrict__ pairs) {
    __shared__ int hist[NB];
    __shared__ int start_s[NB];
    __shared__ int lcur[NB];
    int tid = threadIdx.x;
    int e0 = blockIdx.x * CHUNK;
    for (int b = tid; b < NB; b += 256) hist[b] = 0;
    __syncthreads();
    #pragma unroll 4
    for (int k = 0; k < CHUNK / 256; ++k) {
        int e = e0 + k * 256 + tid;
        if (e < E) atomicAdd(&hist[ei[E + e] >> 7], 1);
    }
    __syncthreads();
    for (int b = tid; b < NB; b += 256) {
        if (hist[b]) start_s[b] = atomicAdd(&bcursor[b], hist[b]);
        lcur[b] = 0;
    }
    __syncthreads();
    #pragma unroll 4
    for (int k = 0; k < CHUNK / 256; ++k) {
        int e = e0 + k * 256 + tid;
        if (e < E) {
            int d = ei[E + e];
            int s = ei[e];
            int b = d >> 7;
            int pos = start_s[b] + atomicAdd(&lcur[b], 1);
            if (pos < (b + 1) * CAP) pairs[pos] = (s << 7) | (d & 127);
        }
    }
}

// ---------------- CSR build, phase 2: per-bucket local CSR in LDS (128 nodes/bucket) ----
__global__ __launch_bounds__(256) void csr_bucket_kernel(const int* __restrict__ pairs,
                                                         const int* __restrict__ bcursor,
                                                         int* __restrict__ srcs,
                                                         int2* __restrict__ nrange) {
    __shared__ int cnt_l[BW];
    __shared__ int cur_l[BW];
    __shared__ int wt[2];
    int b = blockIdx.x;
    int tid = threadIdx.x;
    int base = b * CAP;
    int cnt = bcursor[b] - base;
    if (cnt > CAP) cnt = CAP;
    if (tid < BW) cnt_l[tid] = 0;
    __syncthreads();
    for (int i = tid; i < cnt; i += 256) {
        atomicAdd(&cnt_l[pairs[base + i] & 127], 1);
    }
    __syncthreads();
    if (tid < BW) {
        int v = cnt_l[tid];
        int lane = tid & 63, w = tid >> 6;
        int incl = v;
        #pragma unroll
        for (int off = 1; off < 64; off <<= 1) {
            int t = __shfl_up(incl, off);
            if (lane >= off) incl += t;
        }
        if (lane == 63) wt[w] = incl;
        __syncthreads();
        int excl = (w ? wt[0] : 0) + incl - v;
        int node = b * BW + tid;
        if (node < N) nrange[node] = make_int2(base + excl, base + excl + v);
        cur_l[tid] = excl;
    } else {
        __syncthreads();
    }
    __syncthreads();
    for (int i = tid; i < cnt; i += 256) {
        int p = pairs[base + i];
        int pos = atomicAdd(&cur_l[p & 127], 1);
        srcs[base + pos] = p >> 7;
    }
}

// ---------------- MFMA bf16x3 linear: out = act(in @ W.T + b) ----------------
// IN_SPLIT: 0 = fp32 input (split on stage), 1 = pre-split uint4 table (hi01,hi23,lo01,lo23 per 4 feats; ID=128)
// OUT_MODE: 1 = gelu + bf16-pack table, 2 = gelu + row-L2-normalize + fp32 (OD=64)
template <int ID, int OD, int IN_SPLIT, int OUT_MODE>
__global__ __launch_bounds__(256) void lin_mfma_kernel(const void* __restrict__ in_v,
                                                       const float* __restrict__ W,
                                                       const float* __restrict__ bias,
                                                       void* __restrict__ out_v, int nrows) {
    constexpr int KC = 32;
    constexpr int NCH = ID / KC;
    constexpr int AST = 40;
    constexpr int NCT = OD / 16;
    constexpr int LDSU = 2 * 128 * AST + 2 * OD * AST;
    __shared__ __align__(16) unsigned short lds[LDSU];
    unsigned short* Ahi = lds;
    unsigned short* Alo = lds + 128 * AST;
    unsigned short* Whi = lds + 2 * 128 * AST;
    unsigned short* Wlo = lds + 2 * 128 * AST + OD * AST;

    int tid = threadIdx.x;
    int w = tid >> 6, lane = tid & 63;
    int m15 = lane & 15, quad = lane >> 4;
    int nb = blockIdx.x * 128;

    f32x4 acc[2][NCT];
    #pragma unroll
    for (int rt = 0; rt < 2; ++rt)
        #pragma unroll
        for (int ct = 0; ct < NCT; ++ct) acc[rt][ct] = (f32x4)0.f;

    for (int c = 0; c < NCH; ++c) {
        int kb = c * KC;
        if (IN_SPLIT == 0) {
            const float* in = (const float*)in_v;
            #pragma unroll
            for (int it = 0; it < 4; ++it) {
                int f4 = it * 256 + tid;
                int row = f4 >> 3, kq = (f4 & 7) * 4;
                float4 v = make_float4(0.f, 0.f, 0.f, 0.f);
                if (nb + row < nrows) v = *(const float4*)&in[(size_t)(nb + row) * ID + kb + kq];
                unsigned short h0, h1, h2, h3, l0, l1, l2, l3;
                bfsplit(v.x, h0, l0); bfsplit(v.y, h1, l1);
                bfsplit(v.z, h2, l2); bfsplit(v.w, h3, l3);
                uint2 uh, ul;
                uh.x = (unsigned int)h0 | ((unsigned int)h1 << 16);
                uh.y = (unsigned int)h2 | ((unsigned int)h3 << 16);
                ul.x = (unsigned int)l0 | ((unsigned int)l1 << 16);
                ul.y = (unsigned int)l2 | ((unsigned int)l3 << 16);
                *(uint2*)&Ahi[row * AST + kq] = uh;
                *(uint2*)&Alo[row * AST + kq] = ul;
            }
        } else {
            // pre-split: uint4 per 4-feat group, row = 32 groups (ID=128)
            const uint4* in4 = (const uint4*)in_v;
            #pragma unroll
            for (int it = 0; it < 4; ++it) {
                int i = it * 256 + tid;           // 1024 groups = 128 rows x 8 groups
                int row = i >> 3, grp = i & 7;
                uint4 u = make_uint4(0u, 0u, 0u, 0u);
                if (nb + row < nrows) u = in4[(size_t)(nb + row) * 32 + c * 8 + grp];
                *(uint2*)&Ahi[row * AST + grp * 4] = make_uint2(u.x, u.y);
                *(uint2*)&Alo[row * AST + grp * 4] = make_uint2(u.z, u.w);
            }
        }
        #pragma unroll
        for (int it = 0; it < OD / 32; ++it) {
            int f4 = it * 256 + tid;
            int o = f4 >> 3, kq = (f4 & 7) * 4;
            float4 v = *(const float4*)&W[(size_t)o * ID + kb + kq];
            unsigned short h0, h1, h2, h3, l0, l1, l2, l3;
            bfsplit(v.x, h0, l0); bfsplit(v.y, h1, l1);
            bfsplit(v.z, h2, l2); bfsplit(v.w, h3, l3);
            uint2 uh, ul;
            uh.x = (unsigned int)h0 | ((unsigned int)h1 << 16);
            uh.y = (unsigned int)h2 | ((unsigned int)h3 << 16);
            ul.x = (unsigned int)l0 | ((unsigned int)l1 << 16);
            ul.y = (unsigned int)l2 | ((unsigned int)l3 << 16);
            *(uint2*)&Whi[o * AST + kq] = uh;
            *(uint2*)&Wlo[o * AST + kq] = ul;
        }
        __syncthreads();

        short8 ah0 = *(const short8*)&Ahi[(w * 32 + m15) * AST + quad * 8];
        short8 ah1 = *(const short8*)&Ahi[(w * 32 + 16 + m15) * AST + quad * 8];
        short8 al0 = *(const short8*)&Alo[(w * 32 + m15) * AST + quad * 8];
        short8 al1 = *(const short8*)&Alo[(w * 32 + 16 + m15) * AST + quad * 8];
        #pragma unroll
        for (int ct = 0; ct < NCT; ++ct) {
            short8 bh = *(const short8*)&Whi[(ct * 16 + m15) * AST + quad * 8];
            short8 bl = *(const short8*)&Wlo[(ct * 16 + m15) * AST + quad * 8];
            acc[0][ct] = __builtin_amdgcn_mfma_f32_16x16x32_bf16(ah0, bh, acc[0][ct], 0, 0, 0);
            acc[0][ct] = __builtin_amdgcn_mfma_f32_16x16x32_bf16(ah0, bl, acc[0][ct], 0, 0, 0);
            acc[0][ct] = __builtin_amdgcn_mfma_f32_16x16x32_bf16(al0, bh, acc[0][ct], 0, 0, 0);
            acc[1][ct] = __builtin_amdgcn_mfma_f32_16x16x32_bf16(ah1, bh, acc[1][ct], 0, 0, 0);
            acc[1][ct] = __builtin_amdgcn_mfma_f32_16x16x32_bf16(ah1, bl, acc[1][ct], 0, 0, 0);
            acc[1][ct] = __builtin_amdgcn_mfma_f32_16x16x32_bf16(al1, bh, acc[1][ct], 0, 0, 0);
        }
        __syncthreads();
    }

    float bcol[NCT];
    #pragma unroll
    for (int ct = 0; ct < NCT; ++ct) bcol[ct] = bias[ct * 16 + m15];

    if (OUT_MODE == 1) {
        constexpr int EPS = OD + 8;
        unsigned short* ep = lds;
        #pragma unroll
        for (int rt = 0; rt < 2; ++rt)
            #pragma unroll
            for (int ct = 0; ct < NCT; ++ct)
                #pragma unroll
                for (int r = 0; r < 4; ++r) {
                    int rl = w * 32 + rt * 16 + quad * 4 + r;
                    float v = gelu_f(acc[rt][ct][r] + bcol[ct]);
                    ep[rl * EPS + ct * 16 + m15] = f2bf(v);
                }
        __syncthreads();
        constexpr int U4 = 128 * OD / 8;
        for (int i = tid; i < U4; i += 256) {
            int row = i / (OD / 8);
            int off = (i % (OD / 8)) * 8;
            int grow = nb + row;
            if (grow < nrows) {
                uint4 v = *(const uint4*)&ep[row * EPS + off];
                *(uint4*)((unsigned short*)out_v + (size_t)grow * OD + off) = v;
            }
        }
    } else {
        float* out = (float*)out_v;
        #pragma unroll
        for (int rt = 0; rt < 2; ++rt) {
            #pragma unroll
            for (int r = 0; r < 4; ++r) {
                float vv[NCT];
                float ss = 0.f;
                #pragma unroll
                for (int ct = 0; ct < NCT; ++ct) {
                    vv[ct] = gelu_f(acc[rt][ct][r] + bcol[ct]);
                    ss += vv[ct] * vv[ct];
                }
                #pragma unroll
                for (int mm = 1; mm < 16; mm <<= 1) ss += __shfl_xor(ss, mm);
                float denom = fmaxf(sqrtf(ss), 1e-12f);
                int grow = nb + w * 32 + rt * 16 + quad * 4 + r;
                if (grow < nrows) {
                    #pragma unroll
                    for (int ct = 0; ct < NCT; ++ct)
                        out[(size_t)grow * OD + ct * 16 + m15] = vv[ct] / denom;
                }
            }
        }
    }
}

// ---------------- GIN aggregation (bf16 table, half-wave uint2 gather) ----------------
// writes pre-split table: uint4 per 4-feat group = (hi01, hi23, lo01, lo23)
__global__ __launch_bounds__(256) void agg_kernel(const uint2* __restrict__ hb2,
                                                  const int2* __restrict__ nrange,
                                                  const int* __restrict__ srcs,
                                                  uint4* __restrict__ utab) {
    int wave = threadIdx.x >> 6, lane = threadIdx.x & 63;
    int half = lane >> 5, hl = lane & 31;
    int n = blockIdx.x * 4 + wave;
    if (n >= N) return;
    int2 rng = nrange[n];
    int s0 = rng.x, deg = rng.y - rng.x;
    int m1 = deg < 64 ? deg : 64;
    int pre = (lane < m1) ? srcs[s0 + lane] : 0;
    float a0 = 0.f, a1 = 0.f, a2 = 0.f, a3 = 0.f;
    int t = 0;
    for (; t + 8 <= m1; t += 8) {   // 4 pairs = 8 edges, 4 independent loads
        int i0 = __shfl(pre, t + half);
        int i1 = __shfl(pre, t + 2 + half);
        int i2 = __shfl(pre, t + 4 + half);
        int i3 = __shfl(pre, t + 6 + half);
        uint2 u0 = hb2[(size_t)i0 * 32 + hl];
        uint2 u1 = hb2[(size_t)i1 * 32 + hl];
        uint2 u2 = hb2[(size_t)i2 * 32 + hl];
        uint2 u3 = hb2[(size_t)i3 * 32 + hl];
        a0 += bf_lo(u0.x); a1 += bf_hi(u0.x); a2 += bf_lo(u0.y); a3 += bf_hi(u0.y);
        a0 += bf_lo(u1.x); a1 += bf_hi(u1.x); a2 += bf_lo(u1.y); a3 += bf_hi(u1.y);
        a0 += bf_lo(u2.x); a1 += bf_hi(u2.x); a2 += bf_lo(u2.y); a3 += bf_hi(u2.y);
        a0 += bf_lo(u3.x); a1 += bf_hi(u3.x); a2 += bf_lo(u3.y); a3 += bf_hi(u3.y);
    }
    for (; t < m1; t += 2) {
        int idx = t + half;
        int idc = idx < m1 ? idx : 0;
        int s = __shfl(pre, idc);
        if (idx < m1) {
            uint2 u = hb2[(size_t)s * 32 + hl];
            a0 += bf_lo(u.x); a1 += bf_hi(u.x); a2 += bf_lo(u.y); a3 += bf_hi(u.y);
        }
    }
    for (int j = 64 + half; j < deg; j += 2) {  // statistically never
        int s = srcs[s0 + j];
        uint2 u = hb2[(size_t)s * 32 + hl];
        a0 += bf_lo(u.x); a1 += bf_hi(u.x); a2 += bf_lo(u.y); a3 += bf_hi(u.y);
    }
    a0 += __shfl_down(a0, 32);
    a1 += __shfl_down(a1, 32);
    a2 += __shfl_down(a2, 32);
    a3 += __shfl_down(a3, 32);
    if (half == 0) {
        uint2 u = hb2[(size_t)n * 32 + hl];  // self row (GIN eps=0)
        a0 += bf_lo(u.x); a1 += bf_hi(u.x); a2 += bf_lo(u.y); a3 += bf_hi(u.y);
        unsigned short h0, h1, h2, h3, l0, l1, l2, l3;
        bfsplit(a0, h0, l0); bfsplit(a1, h1, l1);
        bfsplit(a2, h2, l2); bfsplit(a3, h3, l3);
        uint4 o;
        o.x = (unsigned int)h0 | ((unsigned int)h1 << 16);
        o.y = (unsigned int)h2 | ((unsigned int)h3 << 16);
        o.z = (unsigned int)l0 | ((unsigned int)l1 << 16);
        o.w = (unsigned int)l2 | ((unsigned int)l3 << 16);
        utab[(size_t)n * 32 + hl] = o;
    }
}

// ---------------- fused Set2Set: one block per graph, LDS node cache, coalesced WT ----
__global__ __launch_bounds__(256) void set2set_kernel(const float* __restrict__ hn,
                                                      const int* __restrict__ gstart,
                                                      const float* __restrict__ WT0, const float* __restrict__ b0,
                                                      const float* __restrict__ WT1, const float* __restrict__ b1,
                                                      float* __restrict__ qstar_out) {
    __shared__ __align__(16) unsigned short hL[MAXN * RST];  // bf16 node rows
    __shared__ float av[MAXN];
    __shared__ __align__(16) float xc0[192];   // [q_star(128); h0(64)]
    __shared__ __align__(16) float xc1[128];   // [h0(64); h1(64)]
    __shared__ __align__(16) float gates[256];
    __shared__ float c0v[H2], c1v[H2];
    __shared__ float red[4];
    __shared__ float rp[4][H2];
    __shared__ float sp[4];

    int g = blockIdx.x;
    int tid = threadIdx.x, w = tid >> 6, lane = tid & 63;
    int s0 = gstart[g], s1 = gstart[g + 1];
    int cnt = s1 - s0;
    int cL = cnt < MAXN ? cnt : MAXN;
    const float* hq = xc1 + 64;   // q = h1

    for (int idx = tid; idx < cL * 16; idx += 256) {
        int n = idx >> 4, p4 = idx & 15;
        float4 v = *(const float4*)&hn[(size_t)(s0 + n) * 64 + p4 * 4];
        uint2 u;
        u.x = (unsigned int)f2bf(v.x) | ((unsigned int)f2bf(v.y) << 16);
        u.y = (unsigned int)f2bf(v.z) | ((unsigned int)f2bf(v.w) << 16);
        *(uint2*)&hL[n * RST + p4 * 4] = u;
    }
    if (tid < 192) xc0[tid] = 0.f;
    if (tid < 128) xc1[tid] = 0.f;
    if (tid < H2) { c0v[tid] = 0.f; c1v[tid] = 0.f; }
    float b0v = b0[tid], b1v = b1[tid];
    __syncthreads();

    for (int step = 0; step < 4; ++step) {
        // ---- cell 0: x = [q_star; h0] (xc0), coalesced WT0 columns ----
        {
            float a0 = 0.f, a1 = 0.f, a2 = 0.f, a3 = 0.f;
            #pragma unroll 8
            for (int k = 0; k < 192; k += 4) {
                a0 += xc0[k]     * WT0[(k)     * 256 + tid];
                a1 += xc0[k + 1] * WT0[(k + 1) * 256 + tid];
                a2 += xc0[k + 2] * WT0[(k + 2) * 256 + tid];
                a3 += xc0[k + 3] * WT0[(k + 3) * 256 + tid];
            }
            gates[tid] = (a0 + a1) + (a2 + a3) + b0v;
        }
        __syncthreads();
        if (tid < H2) {
            float ii = sigmoid_f(gates[tid]), ff = sigmoid_f(gates[H2 + tid]);
            float gg = tanhf(gates[2 * H2 + tid]), oo = sigmoid_f(gates[3 * H2 + tid]);
            float c = ff * c0v[tid] + ii * gg;
            float h = oo * tanhf(c);
            c0v[tid] = c; xc0[128 + tid] = h; xc1[tid] = h;
        }
        __syncthreads();
        // ---- cell 1: x = [h0; h1] (xc1), coalesced WT1 columns ----
        {
            float a0 = 0.f, a1 = 0.f, a2 = 0.f, a3 = 0.f;
            #pragma unroll 8
            for (int k = 0; k < 128; k += 4) {
                a0 += xc1[k]     * WT1[(k)     * 256 + tid];
                a1 += xc1[k + 1] * WT1[(k + 1) * 256 + tid];
                a2 += xc1[k + 2] * WT1[(k + 2) * 256 + tid];
                a3 += xc1[k + 3] * WT1[(k + 3) * 256 + tid];
            }
            gates[tid] = (a0 + a1) + (a2 + a3) + b1v;
        }
        __syncthreads();
        if (tid < H2) {
            float ii = sigmoid_f(gates[tid]), ff = sigmoid_f(gates[H2 + tid]);
            float gg = tanhf(gates[2 * H2 + tid]), oo = sigmoid_f(gates[3 * H2 + tid]);
            float c = ff * c1v[tid] + ii * gg;
            float h = oo * tanhf(c);
            c1v[tid] = c; xc1[64 + tid] = h;   // h1 == q
        }
        __syncthreads();

        // ---- attention e-phase: one thread per node, dot from LDS ----
        float lm = -INFINITY;
        for (int i = tid; i < cnt; i += 256) {
            float e = 0.f;
            if (i < MAXN) {
                const uint2* row = (const uint2*)&hL[i * RST];
                #pragma unroll
                for (int p4 = 0; p4 < 16; ++p4) {
                    uint2 u = row[p4];
                    e += bf_lo(u.x) * hq[p4 * 4 + 0];
                    e += bf_hi(u.x) * hq[p4 * 4 + 1];
                    e += bf_lo(u.y) * hq[p4 * 4 + 2];
                    e += bf_hi(u.y) * hq[p4 * 4 + 3];
                }
                av[i] = e;
            } else {
                for (int f = 0; f < 64; ++f) e += hn[(size_t)(s0 + i) * 64 + f] * hq[f];
            }
            lm = fmaxf(lm, e);
        }
        #pragma unroll
        for (int mm = 32; mm; mm >>= 1) lm = fmaxf(lm, __shfl_xor(lm, mm));
        if (lane == 0) red[w] = lm;
        __syncthreads();
        float m = fmaxf(fmaxf(red[0], red[1]), fmaxf(red[2], red[3]));

        float ps = 0.f;
        for (int i = tid; i < cnt; i += 256) {
            float e;
            if (i < MAXN) e = av[i];
            else {
                e = 0.f;
                for (int f = 0; f < 64; ++f) e += hn[(size_t)(s0 + i) * 64 + f] * hq[f];
            }
            float p = expf(e - m);
            ps += p;
            if (i < MAXN) av[i] = p;
        }
        ps = waveAllSum(ps);
        if (lane == 0) sp[w] = ps;
        __syncthreads();
        float s = sp[0] + sp[1] + sp[2] + sp[3];

        float racc = 0.f;
        for (int i = w; i < cL; i += 4) {
            unsigned short hv = hL[i * RST + lane];
            racc += av[i] * bf2f(hv);
        }
        float qf = hq[lane];
        for (int n = MAXN + w; n < cnt; n += 4) {
            float v = hn[(size_t)(s0 + n) * 64 + lane];
            float e = waveAllSum(v * qf);
            float p = expf(e - m);
            racc += p * v;
        }
        rp[w][lane] = racc;
        __syncthreads();
        if (tid < H2) {
            float r = 0.f;
            if (cnt > 0) {
                r = (rp[0][tid] + rp[1][tid] + rp[2][tid] + rp[3][tid]) / (s + 1e-16f);
            }
            xc0[tid] = xc1[64 + tid];  // q
            xc0[H2 + tid] = r;         // r
        }
        __syncthreads();
    }
    if (tid < 2 * H2) qstar_out[g * 2 * H2 + tid] = xc0[tid];
}

// ---------------- output head: z = fc2(gelu(fc1(q_star))) ----------------
__global__ __launch_bounds__(256) void fcout_kernel(const float* __restrict__ q_star,
                                                    const float* __restrict__ W1, const float* __restrict__ b1,
                                                    const float* __restrict__ W2, const float* __restrict__ b2,
                                                    float* __restrict__ z) {
    __shared__ float W1l[32 * 128];
    __shared__ float b1l[32], W2l[32];
    int tid = threadIdx.x;
    for (int i = tid; i < 32 * 128; i += 256) W1l[i] = W1[i];
    if (tid < 32) { b1l[tid] = b1[tid]; W2l[tid] = W2[tid]; }
    __syncthreads();
    int g = blockIdx.x * 256 + tid;
    float acc[32];
    #pragma unroll
    for (int j = 0; j < 32; ++j) acc[j] = b1l[j];
    for (int k = 0; k < 128; ++k) {
        float qv = q_star[g * 128 + k];
        #pragma unroll
        for (int j = 0; j < 32; ++j) acc[j] += qv * W1l[j * 128 + k];
    }
    float zv = b2[0];
    #pragma unroll
    for (int j = 0; j < 32; ++j) zv += gelu_f(acc[j]) * W2l[j];
    z[g] = zv;
}

extern "C" void kernel_launch(void* const* d_in, const int* in_sizes, int n_in,
                              void* d_out, int out_size, void* d_ws, size_t ws_size,
                              hipStream_t stream) {
    const float* x       = (const float*)d_in[0];
    const int*   ei      = (const int*)d_in[1];
    const int*   batch   = (const int*)d_in[2];
    const float* nfc_W   = (const float*)d_in[3];
    const float* nfc_b   = (const float*)d_in[4];
    const float* gc1_W   = (const float*)d_in[5];
    const float* gc1_b   = (const float*)d_in[6];
    const float* gc2_W   = (const float*)d_in[7];
    const float* gc2_b   = (const float*)d_in[8];
    const float* l0_Wih  = (const float*)d_in[9];
    const float* l0_Whh  = (const float*)d_in[10];
    const float* l0_bih  = (const float*)d_in[11];
    const float* l0_bhh  = (const float*)d_in[12];
    const float* l1_Wih  = (const float*)d_in[13];
    const float* l1_Whh  = (const float*)d_in[14];
    const float* l1_bih  = (const float*)d_in[15];
    const float* l1_bhh  = (const float*)d_in[16];
    const float* fc1_W   = (const float*)d_in[17];
    const float* fc1_b   = (const float*)d_in[18];
    const float* fc2_W   = (const float*)d_in[19];
    const float* fc2_b   = (const float*)d_in[20];

    float* out = (float*)d_out;          // [0,512): z ; [512, 512+N*64): normalized h
    float* hn_out = out + NG;

    char* p = (char*)d_ws;
    auto take = [&](size_t bytes) {
        char* r = p;
        p += (bytes + 255) & ~size_t(255);
        return r;
    };
    float*        sbuf  = (float*)take((size_t)N * H1 * 4);        // split table s1/s2; aliased as pairs pre-lin
    unsigned int* hbbuf = (unsigned int*)take((size_t)N * H1 * 2); // h1 / h2 (bf16-packed, hi only)
    int*   srcs   = (int*)take((size_t)NB * CAP * 4);
    int2*  nrange = (int2*)take((size_t)N * 8);
    int*   bcursor= (int*)take((size_t)NB * 4);
    int*   gstart = (int*)take((size_t)(NG + 1) * 4);
    float* qstar  = (float*)take((size_t)NG * 2 * H2 * 4);
    float* WT0    = (float*)take((size_t)192 * 256 * 4);
    float* WT1    = (float*)take((size_t)128 * 256 * 4);
    float* b0     = (float*)take((size_t)256 * 4);
    float* b1     = (float*)take((size_t)256 * 4);

    int* pairs = (int*)sbuf;  // NB*CAP*4 = 8.1 MB, free until agg1 writes the split table

    // fused setup (bucket cursors, graph ranges, LSTM weight transpose)
    setup_kernel<<<192, 256, 0, stream>>>(batch, l0_Wih, l0_Whh, l0_bih, l0_bhh,
                                          l1_Wih, l1_Whh, l1_bih, l1_bhh,
                                          WT0, WT1, b0, b1, bcursor, gstart);

    // CSR build (bucket-binned, packed single-int pairs)
    bin_scatter_kernel<<<(E + CHUNK - 1) / CHUNK, 256, 0, stream>>>(ei, bcursor, pairs);
    csr_bucket_kernel<<<NB, 256, 0, stream>>>(pairs, bcursor, srcs, nrange);

    // node feature pipeline (MFMA bf16x3 linears; agg emits pre-split hi/lo table)
    int mfmaGrid = (N + 127) / 128;
    lin_mfma_kernel<NF, H1, 0, 1><<<mfmaGrid, 256, 0, stream>>>(x, nfc_W, nfc_b, hbbuf, N);     // h1 (bf16 hi)
    agg_kernel<<<(N + 3) / 4, 256, 0, stream>>>((const uint2*)hbbuf, nrange, srcs, (uint4*)sbuf);
    lin_mfma_kernel<H1, H1, 1, 1><<<mfmaGrid, 256, 0, stream>>>(sbuf, gc1_W, gc1_b, hbbuf, N);  // h2 (bf16 hi)
    agg_kernel<<<(N + 3) / 4, 256, 0, stream>>>((const uint2*)hbbuf, nrange, srcs, (uint4*)sbuf);
    lin_mfma_kernel<H1, H2, 1, 2><<<mfmaGrid, 256, 0, stream>>>(sbuf, gc2_W, gc2_b, hn_out, N); // normalized h

    // fused Set2Set (all 4 steps, one block per graph, LDS node cache, coalesced WT)
    set2set_kernel<<<NG, 256, 0, stream>>>(hn_out, gstart, WT0, b0, WT1, b1, qstar);

    // head
    fcout_kernel<<<2, 256, 0, stream>>>(qstar, fc1_W, fc1_b, fc2_W, fc2_b, out);
}

// Round 9
// 468.087 us; speedup vs baseline: 1.0138x; 1.0138x over previous
//
#include <hip/hip_runtime.h>
#include <hip/hip_bf16.h>
#include <hip/hip_fp16.h>
#include <math.h>

// Problem constants (fixed by the reference).
constexpr int N  = 100000;   // nodes
constexpr int E  = 1600000;  // edges
constexpr int NG = 512;      // graphs
constexpr int NF = 64;
constexpr int H1 = 128;
constexpr int H2 = 64;

// CSR bucket binning
constexpr int BW   = 128;                 // nodes per bucket (dst >> 7)
constexpr int NB   = (N + BW - 1) / BW;   // 782 buckets
constexpr int CAP  = 2600;                // per-bucket edge capacity (mean 2046 + 12 sigma)
constexpr int CHUNK = 4096;               // edges per bin_scatter block (391 blocks)

// Set2Set LDS node cache
constexpr int MAXN = 416;                 // mean 195 + 15.8 sigma; global fallback beyond
constexpr int RST  = 68;                  // row stride in ushorts

typedef __attribute__((ext_vector_type(8))) short short8;
typedef __attribute__((ext_vector_type(4))) float f32x4;

__device__ __forceinline__ float gelu_f(float x) {
    return 0.5f * x * (1.0f + erff(x * 0.70710678118654752f));
}
__device__ __forceinline__ float sigmoid_f(float x) {
    return 1.0f / (1.0f + expf(-x));
}
__device__ __forceinline__ float waveAllSum(float v) {
    #pragma unroll
    for (int m = 32; m; m >>= 1) v += __shfl_xor(v, m);
    return v;
}
__device__ __forceinline__ unsigned short f2bf(float x) {
    __hip_bfloat16 b = __float2bfloat16(x);
    return *reinterpret_cast<unsigned short*>(&b);
}
__device__ __forceinline__ float bf2f(unsigned short u) {
    return __uint_as_float(((unsigned int)u) << 16);
}
__device__ __forceinline__ float bf_lo(unsigned int u) { return __uint_as_float(u << 16); }
__device__ __forceinline__ float bf_hi(unsigned int u) { return __uint_as_float(u & 0xffff0000u); }

// split v into bf16 hi + bf16 lo (v ~= hi + lo)
__device__ __forceinline__ void bfsplit(float v, unsigned short& hi, unsigned short& lo) {
    hi = f2bf(v);
    lo = f2bf(v - bf2f(hi));
}

// ---------------- fused setup: bucket cursors + graph ranges + LSTM weight transpose ----
__global__ __launch_bounds__(256) void setup_kernel(const int* __restrict__ batch,
                                                    const float* __restrict__ Wih0, const float* __restrict__ Whh0,
                                                    const float* __restrict__ bih0, const float* __restrict__ bhh0,
                                                    const float* __restrict__ Wih1, const float* __restrict__ Whh1,
                                                    const float* __restrict__ bih1, const float* __restrict__ bhh1,
                                                    float* __restrict__ WT0, float* __restrict__ WT1,
                                                    float* __restrict__ b0, float* __restrict__ b1,
                                                    int* __restrict__ bcursor, int* __restrict__ gstart) {
    int i = blockIdx.x * 256 + threadIdx.x;
    if (i < 192 * 256) {
        int k = i >> 8, j = i & 255;
        WT0[i] = (k < 128) ? Wih0[j * 128 + k] : Whh0[j * 64 + (k - 128)];
    }
    if (i < 128 * 256) {
        int k = i >> 8, j = i & 255;
        WT1[i] = (k < 64) ? Wih1[j * 64 + k] : Whh1[j * 64 + (k - 64)];
    }
    if (i < 256) { b0[i] = bih0[i] + bhh0[i]; b1[i] = bih1[i] + bhh1[i]; }
    if (i < NB) bcursor[i] = i * CAP;
    if (i <= NG) {
        if (i == NG) gstart[NG] = N;
        else {
            int lo = 0, hi = N;
            while (lo < hi) {
                int mid = (lo + hi) >> 1;
                if (batch[mid] < i) lo = mid + 1; else hi = mid;
            }
            gstart[i] = lo;
        }
    }
}

// ---------------- CSR build, phase 1: bin edges into bucket-strided packed (src<<7|dstlow) ----
__global__ __launch_bounds__(256) void bin_scatter_kernel(const int* __restrict__ ei,
                                                          int* __restrict__ bcursor,
                                                          int* __restrict__ pairs) {
    __shared__ int hist[NB];
    __shared__ int start_s[NB];
    __shared__ int lcur[NB];
    int tid = threadIdx.x;
    int e0 = blockIdx.x * CHUNK;
    for (int b = tid; b < NB; b += 256) hist[b] = 0;
    __syncthreads();
    #pragma unroll 4
    for (int k = 0; k < CHUNK / 256; ++k) {
        int e = e0 + k * 256 + tid;
        if (e < E) atomicAdd(&hist[ei[E + e] >> 7], 1);
    }
    __syncthreads();
    for (int b = tid; b < NB; b += 256) {
        if (hist[b]) start_s[b] = atomicAdd(&bcursor[b], hist[b]);
        lcur[b] = 0;
    }
    __syncthreads();
    #pragma unroll 4
    for (int k = 0; k < CHUNK / 256; ++k) {
        int e = e0 + k * 256 + tid;
        if (e < E) {
            int d = ei[E + e];
            int s = ei[e];
            int b = d >> 7;
            int pos = start_s[b] + atomicAdd(&lcur[b], 1);
            if (pos < (b + 1) * CAP) pairs[pos] = (s << 7) | (d & 127);
        }
    }
}

// ---------------- CSR build, phase 2: per-bucket local CSR in LDS (128 nodes/bucket) ----
__global__ __launch_bounds__(256) void csr_bucket_kernel(const int* __restrict__ pairs,
                                                         const int* __restrict__ bcursor,
                                                         int* __restrict__ srcs,
                                                         int2* __restrict__ nrange) {
    __shared__ int cnt_l[BW];
    __shared__ int cur_l[BW];
    __shared__ int wt[2];
    int b = blockIdx.x;
    int tid = threadIdx.x;
    int base = b * CAP;
    int cnt = bcursor[b] - base;
    if (cnt > CAP) cnt = CAP;
    if (tid < BW) cnt_l[tid] = 0;
    __syncthreads();
    for (int i = tid; i < cnt; i += 256) {
        atomicAdd(&cnt_l[pairs[base + i] & 127], 1);
    }
    __syncthreads();
    if (tid < BW) {
        int v = cnt_l[tid];
        int lane = tid & 63, w = tid >> 6;
        int incl = v;
        #pragma unroll
        for (int off = 1; off < 64; off <<= 1) {
            int t = __shfl_up(incl, off);
            if (lane >= off) incl += t;
        }
        if (lane == 63) wt[w] = incl;
        __syncthreads();
        int excl = (w ? wt[0] : 0) + incl - v;
        int node = b * BW + tid;
        if (node < N) nrange[node] = make_int2(base + excl, base + excl + v);
        cur_l[tid] = excl;
    } else {
        __syncthreads();
    }
    __syncthreads();
    for (int i = tid; i < cnt; i += 256) {
        int p = pairs[base + i];
        int pos = atomicAdd(&cur_l[p & 127], 1);
        srcs[base + pos] = p >> 7;
    }
}

// ---------------- MFMA bf16x3 linear (lin1 only): out = gelu(in @ W.T + b), bf16-pack ----
template <int ID, int OD>
__global__ __launch_bounds__(256) void lin_mfma_kernel(const float* __restrict__ in,
                                                       const float* __restrict__ W,
                                                       const float* __restrict__ bias,
                                                       unsigned short* __restrict__ out_bf, int nrows) {
    constexpr int KC = 32;
    constexpr int NCH = ID / KC;
    constexpr int AST = 40;
    constexpr int NCT = OD / 16;
    constexpr int LDSU = 2 * 128 * AST + 2 * OD * AST;
    __shared__ __align__(16) unsigned short lds[LDSU];
    unsigned short* Ahi = lds;
    unsigned short* Alo = lds + 128 * AST;
    unsigned short* Whi = lds + 2 * 128 * AST;
    unsigned short* Wlo = lds + 2 * 128 * AST + OD * AST;

    int tid = threadIdx.x;
    int w = tid >> 6, lane = tid & 63;
    int m15 = lane & 15, quad = lane >> 4;
    int nb = blockIdx.x * 128;

    f32x4 acc[2][NCT];
    #pragma unroll
    for (int rt = 0; rt < 2; ++rt)
        #pragma unroll
        for (int ct = 0; ct < NCT; ++ct) acc[rt][ct] = (f32x4)0.f;

    for (int c = 0; c < NCH; ++c) {
        int kb = c * KC;
        #pragma unroll
        for (int it = 0; it < 4; ++it) {
            int f4 = it * 256 + tid;
            int row = f4 >> 3, kq = (f4 & 7) * 4;
            float4 v = make_float4(0.f, 0.f, 0.f, 0.f);
            if (nb + row < nrows) v = *(const float4*)&in[(size_t)(nb + row) * ID + kb + kq];
            unsigned short h0, h1, h2, h3, l0, l1, l2, l3;
            bfsplit(v.x, h0, l0); bfsplit(v.y, h1, l1);
            bfsplit(v.z, h2, l2); bfsplit(v.w, h3, l3);
            uint2 uh, ul;
            uh.x = (unsigned int)h0 | ((unsigned int)h1 << 16);
            uh.y = (unsigned int)h2 | ((unsigned int)h3 << 16);
            ul.x = (unsigned int)l0 | ((unsigned int)l1 << 16);
            ul.y = (unsigned int)l2 | ((unsigned int)l3 << 16);
            *(uint2*)&Ahi[row * AST + kq] = uh;
            *(uint2*)&Alo[row * AST + kq] = ul;
        }
        #pragma unroll
        for (int it = 0; it < OD / 32; ++it) {
            int f4 = it * 256 + tid;
            int o = f4 >> 3, kq = (f4 & 7) * 4;
            float4 v = *(const float4*)&W[(size_t)o * ID + kb + kq];
            unsigned short h0, h1, h2, h3, l0, l1, l2, l3;
            bfsplit(v.x, h0, l0); bfsplit(v.y, h1, l1);
            bfsplit(v.z, h2, l2); bfsplit(v.w, h3, l3);
            uint2 uh, ul;
            uh.x = (unsigned int)h0 | ((unsigned int)h1 << 16);
            uh.y = (unsigned int)h2 | ((unsigned int)h3 << 16);
            ul.x = (unsigned int)l0 | ((unsigned int)l1 << 16);
            ul.y = (unsigned int)l2 | ((unsigned int)l3 << 16);
            *(uint2*)&Whi[o * AST + kq] = uh;
            *(uint2*)&Wlo[o * AST + kq] = ul;
        }
        __syncthreads();

        short8 ah0 = *(const short8*)&Ahi[(w * 32 + m15) * AST + quad * 8];
        short8 ah1 = *(const short8*)&Ahi[(w * 32 + 16 + m15) * AST + quad * 8];
        short8 al0 = *(const short8*)&Alo[(w * 32 + m15) * AST + quad * 8];
        short8 al1 = *(const short8*)&Alo[(w * 32 + 16 + m15) * AST + quad * 8];
        #pragma unroll
        for (int ct = 0; ct < NCT; ++ct) {
            short8 bh = *(const short8*)&Whi[(ct * 16 + m15) * AST + quad * 8];
            short8 bl = *(const short8*)&Wlo[(ct * 16 + m15) * AST + quad * 8];
            acc[0][ct] = __builtin_amdgcn_mfma_f32_16x16x32_bf16(ah0, bh, acc[0][ct], 0, 0, 0);
            acc[0][ct] = __builtin_amdgcn_mfma_f32_16x16x32_bf16(ah0, bl, acc[0][ct], 0, 0, 0);
            acc[0][ct] = __builtin_amdgcn_mfma_f32_16x16x32_bf16(al0, bh, acc[0][ct], 0, 0, 0);
            acc[1][ct] = __builtin_amdgcn_mfma_f32_16x16x32_bf16(ah1, bh, acc[1][ct], 0, 0, 0);
            acc[1][ct] = __builtin_amdgcn_mfma_f32_16x16x32_bf16(ah1, bl, acc[1][ct], 0, 0, 0);
            acc[1][ct] = __builtin_amdgcn_mfma_f32_16x16x32_bf16(al1, bh, acc[1][ct], 0, 0, 0);
        }
        __syncthreads();
    }

    float bcol[NCT];
    #pragma unroll
    for (int ct = 0; ct < NCT; ++ct) bcol[ct] = bias[ct * 16 + m15];

    constexpr int EPS = OD + 8;
    unsigned short* ep = lds;
    #pragma unroll
    for (int rt = 0; rt < 2; ++rt)
        #pragma unroll
        for (int ct = 0; ct < NCT; ++ct)
            #pragma unroll
            for (int r = 0; r < 4; ++r) {
                int rl = w * 32 + rt * 16 + quad * 4 + r;
                float v = gelu_f(acc[rt][ct][r] + bcol[ct]);
                ep[rl * EPS + ct * 16 + m15] = f2bf(v);
            }
    __syncthreads();
    constexpr int U4 = 128 * OD / 8;
    for (int i = tid; i < U4; i += 256) {
        int row = i / (OD / 8);
        int off = (i % (OD / 8)) * 8;
        int grow = nb + row;
        if (grow < nrows) {
            uint4 v = *(const uint4*)&ep[row * EPS + off];
            *(uint4*)(out_bf + (size_t)grow * OD + off) = v;
        }
    }
}

// ---------------- GIN aggregation 1 (bf16 table, half-wave uint2 gather) ----------------
// writes pre-split table: uint4 per 4-feat group = (hi01, hi23, lo01, lo23)
__global__ __launch_bounds__(256) void agg_kernel(const uint2* __restrict__ hb2,
                                                  const int2* __restrict__ nrange,
                                                  const int* __restrict__ srcs,
                                                  uint4* __restrict__ utab) {
    int wave = threadIdx.x >> 6, lane = threadIdx.x & 63;
    int half = lane >> 5, hl = lane & 31;
    int n = blockIdx.x * 4 + wave;
    if (n >= N) return;
    int2 rng = nrange[n];
    int s0 = rng.x, deg = rng.y - rng.x;
    int m1 = deg < 64 ? deg : 64;
    int pre = (lane < m1) ? srcs[s0 + lane] : 0;
    float a0 = 0.f, a1 = 0.f, a2 = 0.f, a3 = 0.f;
    int t = 0;
    for (; t + 8 <= m1; t += 8) {
        int i0 = __shfl(pre, t + half);
        int i1 = __shfl(pre, t + 2 + half);
        int i2 = __shfl(pre, t + 4 + half);
        int i3 = __shfl(pre, t + 6 + half);
        uint2 u0 = hb2[(size_t)i0 * 32 + hl];
        uint2 u1 = hb2[(size_t)i1 * 32 + hl];
        uint2 u2 = hb2[(size_t)i2 * 32 + hl];
        uint2 u3 = hb2[(size_t)i3 * 32 + hl];
        a0 += bf_lo(u0.x); a1 += bf_hi(u0.x); a2 += bf_lo(u0.y); a3 += bf_hi(u0.y);
        a0 += bf_lo(u1.x); a1 += bf_hi(u1.x); a2 += bf_lo(u1.y); a3 += bf_hi(u1.y);
        a0 += bf_lo(u2.x); a1 += bf_hi(u2.x); a2 += bf_lo(u2.y); a3 += bf_hi(u2.y);
        a0 += bf_lo(u3.x); a1 += bf_hi(u3.x); a2 += bf_lo(u3.y); a3 += bf_hi(u3.y);
    }
    for (; t < m1; t += 2) {
        int idx = t + half;
        int idc = idx < m1 ? idx : 0;
        int s = __shfl(pre, idc);
        if (idx < m1) {
            uint2 u = hb2[(size_t)s * 32 + hl];
            a0 += bf_lo(u.x); a1 += bf_hi(u.x); a2 += bf_lo(u.y); a3 += bf_hi(u.y);
        }
    }
    for (int j = 64 + half; j < deg; j += 2) {  // statistically never
        int s = srcs[s0 + j];
        uint2 u = hb2[(size_t)s * 32 + hl];
        a0 += bf_lo(u.x); a1 += bf_hi(u.x); a2 += bf_lo(u.y); a3 += bf_hi(u.y);
    }
    a0 += __shfl_down(a0, 32);
    a1 += __shfl_down(a1, 32);
    a2 += __shfl_down(a2, 32);
    a3 += __shfl_down(a3, 32);
    if (half == 0) {
        uint2 u = hb2[(size_t)n * 32 + hl];  // self row (GIN eps=0)
        a0 += bf_lo(u.x); a1 += bf_hi(u.x); a2 += bf_lo(u.y); a3 += bf_hi(u.y);
        unsigned short h0, h1, h2, h3, l0, l1, l2, l3;
        bfsplit(a0, h0, l0); bfsplit(a1, h1, l1);
        bfsplit(a2, h2, l2); bfsplit(a3, h3, l3);
        uint4 o;
        o.x = (unsigned int)h0 | ((unsigned int)h1 << 16);
        o.y = (unsigned int)h2 | ((unsigned int)h3 << 16);
        o.z = (unsigned int)l0 | ((unsigned int)l1 << 16);
        o.w = (unsigned int)l2 | ((unsigned int)l3 << 16);
        utab[(size_t)n * 32 + hl] = o;
    }
}

// ---------------- fused conv-chain GEMMs: h2 = gelu(W1 s1 + b1); y2 = W2 h2 (fp16 out) ----
// Distributive GIN conv2: lin2(h2 + sum h2_j) = y2 + sum y2_j + b2, applied in agg2_norm.
__global__ __launch_bounds__(256) void lin2_fused_kernel(const uint4* __restrict__ in4,   // s1 pre-split [N][32]
                                                         const float* __restrict__ W1,   // [128][128]
                                                         const float* __restrict__ b1,   // [128]
                                                         const float* __restrict__ W2,   // [64][128]
                                                         unsigned short* __restrict__ y2, // [N][64] fp16
                                                         int nrows) {
    constexpr int AST = 40;
    __shared__ __align__(16) unsigned short lds[4 * 128 * AST];
    unsigned short* Ahi = lds;
    unsigned short* Alo = lds + 128 * AST;
    unsigned short* Whi = lds + 2 * 128 * AST;
    unsigned short* Wlo = lds + 3 * 128 * AST;

    int tid = threadIdx.x;
    int w = tid >> 6, lane = tid & 63;
    int m15 = lane & 15, quad = lane >> 4;
    int nb = blockIdx.x * 128;

    f32x4 acc[2][8];
    #pragma unroll
    for (int rt = 0; rt < 2; ++rt)
        #pragma unroll
        for (int ct = 0; ct < 8; ++ct) acc[rt][ct] = (f32x4)0.f;

    // ---- GEMM1: W1 x s1 ----
    for (int c = 0; c < 4; ++c) {
        #pragma unroll
        for (int it = 0; it < 4; ++it) {
            int i = it * 256 + tid;
            int row = i >> 3, grp = i & 7;
            uint4 u = make_uint4(0u, 0u, 0u, 0u);
            if (nb + row < nrows) u = in4[(size_t)(nb + row) * 32 + c * 8 + grp];
            *(uint2*)&Ahi[row * AST + grp * 4] = make_uint2(u.x, u.y);
            *(uint2*)&Alo[row * AST + grp * 4] = make_uint2(u.z, u.w);
        }
        #pragma unroll
        for (int it = 0; it < 4; ++it) {
            int f4 = it * 256 + tid;
            int o = f4 >> 3, kq = (f4 & 7) * 4;
            float4 v = *(const float4*)&W1[(size_t)o * 128 + c * 32 + kq];
            unsigned short h0, h1, h2, h3, l0, l1, l2, l3;
            bfsplit(v.x, h0, l0); bfsplit(v.y, h1, l1);
            bfsplit(v.z, h2, l2); bfsplit(v.w, h3, l3);
            uint2 uh, ul;
            uh.x = (unsigned int)h0 | ((unsigned int)h1 << 16);
            uh.y = (unsigned int)h2 | ((unsigned int)h3 << 16);
            ul.x = (unsigned int)l0 | ((unsigned int)l1 << 16);
            ul.y = (unsigned int)l2 | ((unsigned int)l3 << 16);
            *(uint2*)&Whi[o * AST + kq] = uh;
            *(uint2*)&Wlo[o * AST + kq] = ul;
        }
        __syncthreads();
        short8 ah0 = *(const short8*)&Ahi[(w * 32 + m15) * AST + quad * 8];
        short8 ah1 = *(const short8*)&Ahi[(w * 32 + 16 + m15) * AST + quad * 8];
        short8 al0 = *(const short8*)&Alo[(w * 32 + m15) * AST + quad * 8];
        short8 al1 = *(const short8*)&Alo[(w * 32 + 16 + m15) * AST + quad * 8];
        #pragma unroll
        for (int ct = 0; ct < 8; ++ct) {
            short8 bh = *(const short8*)&Whi[(ct * 16 + m15) * AST + quad * 8];
            short8 bl = *(const short8*)&Wlo[(ct * 16 + m15) * AST + quad * 8];
            acc[0][ct] = __builtin_amdgcn_mfma_f32_16x16x32_bf16(ah0, bh, acc[0][ct], 0, 0, 0);
            acc[0][ct] = __builtin_amdgcn_mfma_f32_16x16x32_bf16(ah0, bl, acc[0][ct], 0, 0, 0);
            acc[0][ct] = __builtin_amdgcn_mfma_f32_16x16x32_bf16(al0, bh, acc[0][ct], 0, 0, 0);
            acc[1][ct] = __builtin_amdgcn_mfma_f32_16x16x32_bf16(ah1, bh, acc[1][ct], 0, 0, 0);
            acc[1][ct] = __builtin_amdgcn_mfma_f32_16x16x32_bf16(ah1, bl, acc[1][ct], 0, 0, 0);
            acc[1][ct] = __builtin_amdgcn_mfma_f32_16x16x32_bf16(al1, bh, acc[1][ct], 0, 0, 0);
        }
        __syncthreads();
    }

    // h2 = gelu(acc + b1) in place
    #pragma unroll
    for (int ct = 0; ct < 8; ++ct) {
        float bc = b1[ct * 16 + m15];
        #pragma unroll
        for (int rt = 0; rt < 2; ++rt)
            #pragma unroll
            for (int r = 0; r < 4; ++r)
                acc[rt][ct][r] = gelu_f(acc[rt][ct][r] + bc);
    }

    // ---- GEMM2: y2 = W2 x h2 (K = 128 over h2 feats, 4 chunks of 32) ----
    f32x4 acc2[2][4];
    #pragma unroll
    for (int rt = 0; rt < 2; ++rt)
        #pragma unroll
        for (int ct = 0; ct < 4; ++ct) acc2[rt][ct] = (f32x4)0.f;

    for (int c2 = 0; c2 < 4; ++c2) {
        __syncthreads();  // protect A/W areas from prior chunk's reads
        // restage h2 cols [c2*32, c2*32+32) from C-layout regs into A-fragment layout
        #pragma unroll
        for (int rt = 0; rt < 2; ++rt)
            #pragma unroll
            for (int cc = 0; cc < 2; ++cc) {
                int ct = c2 * 2 + cc;
                #pragma unroll
                for (int r = 0; r < 4; ++r) {
                    int node = w * 32 + rt * 16 + quad * 4 + r;
                    unsigned short hi, lo;
                    bfsplit(acc[rt][ct][r], hi, lo);
                    Ahi[node * AST + cc * 16 + m15] = hi;
                    Alo[node * AST + cc * 16 + m15] = lo;
                }
            }
        // stage W2 chunk: 64 rows x 32 k
        #pragma unroll
        for (int it = 0; it < 2; ++it) {
            int f4 = it * 256 + tid;
            int o = f4 >> 3, kq = (f4 & 7) * 4;
            float4 v = *(const float4*)&W2[(size_t)o * 128 + c2 * 32 + kq];
            unsigned short h0, h1, h2, h3, l0, l1, l2, l3;
            bfsplit(v.x, h0, l0); bfsplit(v.y, h1, l1);
            bfsplit(v.z, h2, l2); bfsplit(v.w, h3, l3);
            uint2 uh, ul;
            uh.x = (unsigned int)h0 | ((unsigned int)h1 << 16);
            uh.y = (unsigned int)h2 | ((unsigned int)h3 << 16);
            ul.x = (unsigned int)l0 | ((unsigned int)l1 << 16);
            ul.y = (unsigned int)l2 | ((unsigned int)l3 << 16);
            *(uint2*)&Whi[o * AST + kq] = uh;
            *(uint2*)&Wlo[o * AST + kq] = ul;
        }
        __syncthreads();
        short8 ah0 = *(const short8*)&Ahi[(w * 32 + m15) * AST + quad * 8];
        short8 ah1 = *(const short8*)&Ahi[(w * 32 + 16 + m15) * AST + quad * 8];
        short8 al0 = *(const short8*)&Alo[(w * 32 + m15) * AST + quad * 8];
        short8 al1 = *(const short8*)&Alo[(w * 32 + 16 + m15) * AST + quad * 8];
        #pragma unroll
        for (int ct = 0; ct < 4; ++ct) {
            short8 bh = *(const short8*)&Whi[(ct * 16 + m15) * AST + quad * 8];
            short8 bl = *(const short8*)&Wlo[(ct * 16 + m15) * AST + quad * 8];
            acc2[0][ct] = __builtin_amdgcn_mfma_f32_16x16x32_bf16(ah0, bh, acc2[0][ct], 0, 0, 0);
            acc2[0][ct] = __builtin_amdgcn_mfma_f32_16x16x32_bf16(ah0, bl, acc2[0][ct], 0, 0, 0);
            acc2[0][ct] = __builtin_amdgcn_mfma_f32_16x16x32_bf16(al0, bh, acc2[0][ct], 0, 0, 0);
            acc2[1][ct] = __builtin_amdgcn_mfma_f32_16x16x32_bf16(ah1, bh, acc2[1][ct], 0, 0, 0);
            acc2[1][ct] = __builtin_amdgcn_mfma_f32_16x16x32_bf16(ah1, bl, acc2[1][ct], 0, 0, 0);
            acc2[1][ct] = __builtin_amdgcn_mfma_f32_16x16x32_bf16(al1, bh, acc2[1][ct], 0, 0, 0);
        }
    }
    __syncthreads();

    // epilogue: y2 fp16, restage for coalesced uint4 writes (no bias/act here)
    constexpr int EPS = 72;
    unsigned short* ep = lds;
    #pragma unroll
    for (int rt = 0; rt < 2; ++rt)
        #pragma unroll
        for (int ct = 0; ct < 4; ++ct)
            #pragma unroll
            for (int r = 0; r < 4; ++r) {
                int rl = w * 32 + rt * 16 + quad * 4 + r;
                __half hv = __float2half(acc2[rt][ct][r]);
                ep[rl * EPS + ct * 16 + m15] = *reinterpret_cast<unsigned short*>(&hv);
            }
    __syncthreads();
    for (int i = tid; i < 1024; i += 256) {
        int row = i >> 3, off = (i & 7) * 8;
        int grow = nb + row;
        if (grow < nrows)
            *(uint4*)(y2 + (size_t)grow * 64 + off) = *(const uint4*)&ep[row * EPS + off];
    }
}

// ---------------- agg2 + bias + gelu + L2-normalize (fp16 64-dim table, quarter-wave) ----
__global__ __launch_bounds__(256) void agg2_norm_kernel(const uint2* __restrict__ y2,   // [N][16] = 64 fp16
                                                        const int2* __restrict__ nrange,
                                                        const int* __restrict__ srcs,
                                                        const float* __restrict__ b2,
                                                        float* __restrict__ hn) {
    int wave = threadIdx.x >> 6, lane = threadIdx.x & 63;
    int qw = lane >> 4, ql = lane & 15;
    int n = blockIdx.x * 4 + wave;
    if (n >= N) return;
    int2 rng = nrange[n];
    int s0 = rng.x, deg = rng.y - rng.x;
    int m1 = deg < 64 ? deg : 64;
    int pre = (lane < m1) ? srcs[s0 + lane] : 0;
    float a0 = 0.f, a1 = 0.f, a2 = 0.f, a3 = 0.f;
    auto addu = [&](uint2 u) {
        float2 f01 = __half22float2(*reinterpret_cast<__half2*>(&u.x));
        float2 f23 = __half22float2(*reinterpret_cast<__half2*>(&u.y));
        a0 += f01.x; a1 += f01.y; a2 += f23.x; a3 += f23.y;
    };
    int t = 0;
    for (; t + 8 <= m1; t += 8) {   // 2 quads of 4 edges = 8 edges, 2 loads in flight
        int i0 = __shfl(pre, t + qw);
        int i1 = __shfl(pre, t + 4 + qw);
        uint2 u0 = y2[(size_t)i0 * 16 + ql];
        uint2 u1 = y2[(size_t)i1 * 16 + ql];
        addu(u0); addu(u1);
    }
    for (; t < m1; t += 4) {
        int idx = t + qw;
        int s = __shfl(pre, idx < m1 ? idx : 0);
        if (idx < m1) addu(y2[(size_t)s * 16 + ql]);
    }
    for (int j = 64 + qw; j < deg; j += 4) addu(y2[(size_t)srcs[s0 + j] * 16 + ql]);  // never
    a0 += __shfl_down(a0, 32); a1 += __shfl_down(a1, 32);
    a2 += __shfl_down(a2, 32); a3 += __shfl_down(a3, 32);
    a0 += __shfl_down(a0, 16); a1 += __shfl_down(a1, 16);
    a2 += __shfl_down(a2, 16); a3 += __shfl_down(a3, 16);
    if (qw == 0) {
        addu(y2[(size_t)n * 16 + ql]);   // self row (GIN eps=0, W2 pre-applied)
        float4 bv = *(const float4*)&b2[ql * 4];
        float v0 = gelu_f(a0 + bv.x), v1 = gelu_f(a1 + bv.y);
        float v2 = gelu_f(a2 + bv.z), v3 = gelu_f(a3 + bv.w);
        float ss = v0 * v0 + v1 * v1 + v2 * v2 + v3 * v3;
        #pragma unroll
        for (int mm = 1; mm < 16; mm <<= 1) ss += __shfl_xor(ss, mm);
        float d = fmaxf(sqrtf(ss), 1e-12f);
        *(float4*)&hn[(size_t)n * 64 + ql * 4] = make_float4(v0 / d, v1 / d, v2 / d, v3 / d);
    }
}

// ---------------- fused Set2Set: one block per graph, LDS node cache, coalesced WT ----
__global__ __launch_bounds__(256) void set2set_kernel(const float* __restrict__ hn,
                                                      const int* __restrict__ gstart,
                                                      const float* __restrict__ WT0, const float* __restrict__ b0,
                                                      const float* __restrict__ WT1, const float* __restrict__ b1,
                                                      float* __restrict__ qstar_out) {
    __shared__ __align__(16) unsigned short hL[MAXN * RST];  // bf16 node rows
    __shared__ float av[MAXN];
    __shared__ __align__(16) float xc0[192];   // [q_star(128); h0(64)]
    __shared__ __align__(16) float xc1[128];   // [h0(64); h1(64)]
    __shared__ __align__(16) float gates[256];
    __shared__ float c0v[H2], c1v[H2];
    __shared__ float red[4];
    __shared__ float rp[4][H2];
    __shared__ float sp[4];

    int g = blockIdx.x;
    int tid = threadIdx.x, w = tid >> 6, lane = tid & 63;
    int s0 = gstart[g], s1 = gstart[g + 1];
    int cnt = s1 - s0;
    int cL = cnt < MAXN ? cnt : MAXN;
    const float* hq = xc1 + 64;   // q = h1

    for (int idx = tid; idx < cL * 16; idx += 256) {
        int n = idx >> 4, p4 = idx & 15;
        float4 v = *(const float4*)&hn[(size_t)(s0 + n) * 64 + p4 * 4];
        uint2 u;
        u.x = (unsigned int)f2bf(v.x) | ((unsigned int)f2bf(v.y) << 16);
        u.y = (unsigned int)f2bf(v.z) | ((unsigned int)f2bf(v.w) << 16);
        *(uint2*)&hL[n * RST + p4 * 4] = u;
    }
    if (tid < 192) xc0[tid] = 0.f;
    if (tid < 128) xc1[tid] = 0.f;
    if (tid < H2) { c0v[tid] = 0.f; c1v[tid] = 0.f; }
    float b0v = b0[tid], b1v = b1[tid];
    __syncthreads();

    for (int step = 0; step < 4; ++step) {
        {
            float a0 = 0.f, a1 = 0.f, a2 = 0.f, a3 = 0.f;
            #pragma unroll 8
            for (int k = 0; k < 192; k += 4) {
                a0 += xc0[k]     * WT0[(k)     * 256 + tid];
                a1 += xc0[k + 1] * WT0[(k + 1) * 256 + tid];
                a2 += xc0[k + 2] * WT0[(k + 2) * 256 + tid];
                a3 += xc0[k + 3] * WT0[(k + 3) * 256 + tid];
            }
            gates[tid] = (a0 + a1) + (a2 + a3) + b0v;
        }
        __syncthreads();
        if (tid < H2) {
            float ii = sigmoid_f(gates[tid]), ff = sigmoid_f(gates[H2 + tid]);
            float gg = tanhf(gates[2 * H2 + tid]), oo = sigmoid_f(gates[3 * H2 + tid]);
            float c = ff * c0v[tid] + ii * gg;
            float h = oo * tanhf(c);
            c0v[tid] = c; xc0[128 + tid] = h; xc1[tid] = h;
        }
        __syncthreads();
        {
            float a0 = 0.f, a1 = 0.f, a2 = 0.f, a3 = 0.f;
            #pragma unroll 8
            for (int k = 0; k < 128; k += 4) {
                a0 += xc1[k]     * WT1[(k)     * 256 + tid];
                a1 += xc1[k + 1] * WT1[(k + 1) * 256 + tid];
                a2 += xc1[k + 2] * WT1[(k + 2) * 256 + tid];
                a3 += xc1[k + 3] * WT1[(k + 3) * 256 + tid];
            }
            gates[tid] = (a0 + a1) + (a2 + a3) + b1v;
        }
        __syncthreads();
        if (tid < H2) {
            float ii = sigmoid_f(gates[tid]), ff = sigmoid_f(gates[H2 + tid]);
            float gg = tanhf(gates[2 * H2 + tid]), oo = sigmoid_f(gates[3 * H2 + tid]);
            float c = ff * c1v[tid] + ii * gg;
            float h = oo * tanhf(c);
            c1v[tid] = c; xc1[64 + tid] = h;   // h1 == q
        }
        __syncthreads();

        float lm = -INFINITY;
        for (int i = tid; i < cnt; i += 256) {
            float e = 0.f;
            if (i < MAXN) {
                const uint2* row = (const uint2*)&hL[i * RST];
                #pragma unroll
                for (int p4 = 0; p4 < 16; ++p4) {
                    uint2 u = row[p4];
                    e += bf_lo(u.x) * hq[p4 * 4 + 0];
                    e += bf_hi(u.x) * hq[p4 * 4 + 1];
                    e += bf_lo(u.y) * hq[p4 * 4 + 2];
                    e += bf_hi(u.y) * hq[p4 * 4 + 3];
                }
                av[i] = e;
            } else {
                for (int f = 0; f < 64; ++f) e += hn[(size_t)(s0 + i) * 64 + f] * hq[f];
            }
            lm = fmaxf(lm, e);
        }
        #pragma unroll
        for (int mm = 32; mm; mm >>= 1) lm = fmaxf(lm, __shfl_xor(lm, mm));
        if (lane == 0) red[w] = lm;
        __syncthreads();
        float m = fmaxf(fmaxf(red[0], red[1]), fmaxf(red[2], red[3]));

        float ps = 0.f;
        for (int i = tid; i < cnt; i += 256) {
            float e;
            if (i < MAXN) e = av[i];
            else {
                e = 0.f;
                for (int f = 0; f < 64; ++f) e += hn[(size_t)(s0 + i) * 64 + f] * hq[f];
            }
            float p = expf(e - m);
            ps += p;
            if (i < MAXN) av[i] = p;
        }
        ps = waveAllSum(ps);
        if (lane == 0) sp[w] = ps;
        __syncthreads();
        float s = sp[0] + sp[1] + sp[2] + sp[3];

        float racc = 0.f;
        for (int i = w; i < cL; i += 4) {
            unsigned short hv = hL[i * RST + lane];
            racc += av[i] * bf2f(hv);
        }
        float qf = hq[lane];
        for (int n = MAXN + w; n < cnt; n += 4) {
            float v = hn[(size_t)(s0 + n) * 64 + lane];
            float e = waveAllSum(v * qf);
            float p = expf(e - m);
            racc += p * v;
        }
        rp[w][lane] = racc;
        __syncthreads();
        if (tid < H2) {
            float r = 0.f;
            if (cnt > 0) {
                r = (rp[0][tid] + rp[1][tid] + rp[2][tid] + rp[3][tid]) / (s + 1e-16f);
            }
            xc0[tid] = xc1[64 + tid];  // q
            xc0[H2 + tid] = r;         // r
        }
        __syncthreads();
    }
    if (tid < 2 * H2) qstar_out[g * 2 * H2 + tid] = xc0[tid];
}

// ---------------- output head: z = fc2(gelu(fc1(q_star))) ----------------
__global__ __launch_bounds__(256) void fcout_kernel(const float* __restrict__ q_star,
                                                    const float* __restrict__ W1, const float* __restrict__ b1,
                                                    const float* __restrict__ W2, const float* __restrict__ b2,
                                                    float* __restrict__ z) {
    __shared__ float W1l[32 * 128];
    __shared__ float b1l[32], W2l[32];
    int tid = threadIdx.x;
    for (int i = tid; i < 32 * 128; i += 256) W1l[i] = W1[i];
    if (tid < 32) { b1l[tid] = b1[tid]; W2l[tid] = W2[tid]; }
    __syncthreads();
    int g = blockIdx.x * 256 + tid;
    float acc[32];
    #pragma unroll
    for (int j = 0; j < 32; ++j) acc[j] = b1l[j];
    for (int k = 0; k < 128; ++k) {
        float qv = q_star[g * 128 + k];
        #pragma unroll
        for (int j = 0; j < 32; ++j) acc[j] += qv * W1l[j * 128 + k];
    }
    float zv = b2[0];
    #pragma unroll
    for (int j = 0; j < 32; ++j) zv += gelu_f(acc[j]) * W2l[j];
    z[g] = zv;
}

extern "C" void kernel_launch(void* const* d_in, const int* in_sizes, int n_in,
                              void* d_out, int out_size, void* d_ws, size_t ws_size,
                              hipStream_t stream) {
    const float* x       = (const float*)d_in[0];
    const int*   ei      = (const int*)d_in[1];
    const int*   batch   = (const int*)d_in[2];
    const float* nfc_W   = (const float*)d_in[3];
    const float* nfc_b   = (const float*)d_in[4];
    const float* gc1_W   = (const float*)d_in[5];
    const float* gc1_b   = (const float*)d_in[6];
    const float* gc2_W   = (const float*)d_in[7];
    const float* gc2_b   = (const float*)d_in[8];
    const float* l0_Wih  = (const float*)d_in[9];
    const float* l0_Whh  = (const float*)d_in[10];
    const float* l0_bih  = (const float*)d_in[11];
    const float* l0_bhh  = (const float*)d_in[12];
    const float* l1_Wih  = (const float*)d_in[13];
    const float* l1_Whh  = (const float*)d_in[14];
    const float* l1_bih  = (const float*)d_in[15];
    const float* l1_bhh  = (const float*)d_in[16];
    const float* fc1_W   = (const float*)d_in[17];
    const float* fc1_b   = (const float*)d_in[18];
    const float* fc2_W   = (const float*)d_in[19];
    const float* fc2_b   = (const float*)d_in[20];

    float* out = (float*)d_out;          // [0,512): z ; [512, 512+N*64): normalized h
    float* hn_out = out + NG;

    char* p = (char*)d_ws;
    auto take = [&](size_t bytes) {
        char* r = p;
        p += (bytes + 255) & ~size_t(255);
        return r;
    };
    float*          sbuf  = (float*)take((size_t)N * H1 * 4);          // s1 pre-split table; aliased as pairs pre-lin
    unsigned short* hbbuf = (unsigned short*)take((size_t)N * H1 * 2); // h1 bf16 table; later y2 fp16 table
    int*   srcs   = (int*)take((size_t)NB * CAP * 4);
    int2*  nrange = (int2*)take((size_t)N * 8);
    int*   bcursor= (int*)take((size_t)NB * 4);
    int*   gstart = (int*)take((size_t)(NG + 1) * 4);
    float* qstar  = (float*)take((size_t)NG * 2 * H2 * 4);
    float* WT0    = (float*)take((size_t)192 * 256 * 4);
    float* WT1    = (float*)take((size_t)128 * 256 * 4);
    float* b0     = (float*)take((size_t)256 * 4);
    float* b1     = (float*)take((size_t)256 * 4);

    int* pairs = (int*)sbuf;  // NB*CAP*4 = 8.1 MB, free until agg1 writes the split table

    // fused setup (bucket cursors, graph ranges, LSTM weight transpose)
    setup_kernel<<<192, 256, 0, stream>>>(batch, l0_Wih, l0_Whh, l0_bih, l0_bhh,
                                          l1_Wih, l1_Whh, l1_bih, l1_bhh,
                                          WT0, WT1, b0, b1, bcursor, gstart);

    // CSR build (bucket-binned, packed single-int pairs)
    bin_scatter_kernel<<<(E + CHUNK - 1) / CHUNK, 256, 0, stream>>>(ei, bcursor, pairs);
    csr_bucket_kernel<<<NB, 256, 0, stream>>>(pairs, bcursor, srcs, nrange);

    // node feature pipeline
    int mfmaGrid = (N + 127) / 128;
    lin_mfma_kernel<NF, H1><<<mfmaGrid, 256, 0, stream>>>(x, nfc_W, nfc_b, hbbuf, N);          // h1 (bf16 table)
    agg_kernel<<<(N + 3) / 4, 256, 0, stream>>>((const uint2*)hbbuf, nrange, srcs, (uint4*)sbuf); // s1 (pre-split)
    lin2_fused_kernel<<<mfmaGrid, 256, 0, stream>>>((const uint4*)sbuf, gc1_W, gc1_b, gc2_W,
                                                    hbbuf, N);                                  // y2 = W2*gelu(W1*s1+b1) (fp16)
    agg2_norm_kernel<<<(N + 3) / 4, 256, 0, stream>>>((const uint2*)hbbuf, nrange, srcs,
                                                      gc2_b, hn_out);                           // normalized h

    // fused Set2Set (all 4 steps, one block per graph, LDS node cache, coalesced WT)
    set2set_kernel<<<NG, 256, 0, stream>>>(hn_out, gstart, WT0, b0, WT1, b1, qstar);

    // head
    fcout_kernel<<<2, 256, 0, stream>>>(qstar, fc1_W, fc1_b, fc2_W, fc2_b, out);
}